// Round 2
// baseline (22777.786 us; speedup 1.0000x reference)
//
#include <hip/hip_runtime.h>
#include <float.h>

#define V 50000
#define E 100
#define H 512
#define T 200
#define B 256
#define NC 5
#define HB (H * B)

// ---------------- activations (fast, ~2e-7 abs err) ----------------
__device__ __forceinline__ float fsig(float x)  { return 1.f / (1.f + __expf(-x)); }
__device__ __forceinline__ float ftanh(float x) { return 1.f - 2.f / (__expf(2.f * x) + 1.f); }

// ---------------- init: zero states, hmax=-FLT_MAX, last[b] ----------------
// ws layout (floats): h0[2][H][B] | c0[H][B] | h1[2][H][B] | c1[H][B] | hmax[H][B] | last[B](int)
__global__ void k_init(float* __restrict__ ws, const int* __restrict__ X,
                       int* __restrict__ last) {
    int i = blockIdx.x * 256 + threadIdx.x;
    if (i < 6 * HB)       ws[i] = 0.f;         // h0 (2 slots), c0, h1 (2 slots), c1
    else if (i < 7 * HB)  ws[i] = -FLT_MAX;    // hmax
    if (i < B) {
        int l = -1;
        const int* xr = X + i * T;
        for (int t = 0; t < T; ++t)
            if (xr[t] != V) l = t;
        last[i] = l;
    }
}

// ---------------- GEMM pieces ----------------
// acc[jj][g] for wave's 2 j's x 4 gates.  Weight rows r = jj*4+g -> row (g*H + j0+jj),
// addresses are wave-uniform -> s_load; A is [k][B] pre-offset to lane's b.

__device__ __forceinline__ void fma8(float (&acc)[2][4], float a, const float4& wv, int r) {
    // unreachable generic, specialized below
}

__device__ __forceinline__ void accum_vec(float (&acc)[2][4], float4 a,
                                          const float4* const (&wr)[8], int q) {
#pragma unroll
    for (int r = 0; r < 8; ++r) {
        float4 wv = wr[r][q];
        acc[r >> 2][r & 3] = fmaf(a.x, wv.x, acc[r >> 2][r & 3]);
        acc[r >> 2][r & 3] = fmaf(a.y, wv.y, acc[r >> 2][r & 3]);
        acc[r >> 2][r & 3] = fmaf(a.z, wv.z, acc[r >> 2][r & 3]);
        acc[r >> 2][r & 3] = fmaf(a.w, wv.w, acc[r >> 2][r & 3]);
    }
}

// A: [K][B] layout, already offset to this lane's b (so A[k*B] is h[k][b]).
__device__ __forceinline__ void gemm_tb(float (&acc)[2][4], const float* __restrict__ A,
                                        const float4* const (&wr)[8], int K4) {
#pragma unroll 2
    for (int q = 0; q < K4; ++q) {
        float a0 = A[0 * B];
        float a1 = A[1 * B];
        float a2 = A[2 * B];
        float a3 = A[3 * B];
        A += 4 * B;
#pragma unroll
        for (int r = 0; r < 8; ++r) {
            float4 wv = wr[r][q];
            acc[r >> 2][r & 3] = fmaf(a0, wv.x, acc[r >> 2][r & 3]);
            acc[r >> 2][r & 3] = fmaf(a1, wv.y, acc[r >> 2][r & 3]);
            acc[r >> 2][r & 3] = fmaf(a2, wv.z, acc[r >> 2][r & 3]);
            acc[r >> 2][r & 3] = fmaf(a3, wv.w, acc[r >> 2][r & 3]);
        }
    }
}

__device__ __forceinline__ void epilogue(float (&acc)[2][4], const float* __restrict__ bias,
                                         int j0, float* __restrict__ c,
                                         float* __restrict__ hn, int b,
                                         float* __restrict__ hmax,
                                         const int* __restrict__ last, int tt) {
#pragma unroll
    for (int jj = 0; jj < 2; ++jj) {
        int j = j0 + jj;
        float gi = fsig (acc[jj][0] + bias[0 * H + j]);
        float gf = fsig (acc[jj][1] + bias[1 * H + j]);
        float gg = ftanh(acc[jj][2] + bias[2 * H + j]);
        float go = fsig (acc[jj][3] + bias[3 * H + j]);
        float cp = c[j * B + b];
        float cn = gf * cp + gi * gg;
        float hv = go * ftanh(cn);
        c[j * B + b]  = cn;
        hn[j * B + b] = hv;
        if (hmax != nullptr) {
            if (tt <= last[b]) {
                float m = hmax[j * B + b];
                hmax[j * B + b] = fmaxf(m, hv);
            }
        }
    }
}

// ---------------- combined step: blocks 0..255 = layer0(t), 256..511 = layer1(t-1) ----
__global__ __launch_bounds__(256, 2) void k_step(
    int t,
    const int* __restrict__ X, const float* __restrict__ emb,
    const float* __restrict__ Wih0, const float* __restrict__ Whh0,
    const float* __restrict__ b0,
    const float* __restrict__ Wih1, const float* __restrict__ Whh1,
    const float* __restrict__ b1,
    float* __restrict__ ws)
{
    const int bid  = blockIdx.x;
    const int lane = threadIdx.x & 63;
    const int w    = __builtin_amdgcn_readfirstlane((int)(threadIdx.x >> 6)); // wave id 0..3

    float* h0   = ws;                 // 2 slots
    float* c0   = ws + 2 * HB;
    float* h1   = ws + 3 * HB;        // 2 slots
    float* c1   = ws + 5 * HB;
    float* hmax = ws + 6 * HB;
    const int* last = (const int*)(ws + 7 * HB);

    const bool isL1 = bid >= 256;
    const int  b2   = isL1 ? bid - 256 : bid;
    const int  jt   = b2 >> 2;          // 0..63 j-tile (8 j's per block)
    const int  bt   = b2 & 3;           // 0..3  b-tile (64 b's per block)
    const int  j0   = jt * 8 + 2 * w;   // this wave's first j
    const int  b    = bt * 64 + lane;   // this lane's batch row

    float acc[2][4] = {{0.f, 0.f, 0.f, 0.f}, {0.f, 0.f, 0.f, 0.f}};

    if (!isL1) {
        if (t >= T) return;
        const float* A_h = h0 + ((t + 1) & 1) * HB + b;   // h0[t-1]
        float*       hn  = h0 + (t & 1) * HB;             // h0[t]

        const float4* wx[8];
        const float4* wh[8];
#pragma unroll
        for (int r = 0; r < 8; ++r) {
            int row = (r & 3) * H + j0 + (r >> 2);
            wx[r] = (const float4*)(Wih0 + (size_t)row * E);
            wh[r] = (const float4*)(Whh0 + (size_t)row * H);
        }
        // x-part: embedding row gather (per-lane row, 25 float4)
        const float4* er = (const float4*)(emb + (size_t)X[b * T + t] * E);
#pragma unroll 5
        for (int q = 0; q < E / 4; ++q) {
            float4 xa = er[q];
            accum_vec(acc, xa, wx, q);
        }
        // h-part: K = 512
        gemm_tb(acc, A_h, wh, H / 4);
        epilogue(acc, b0, j0, c0, hn, b, nullptr, nullptr, 0);
    } else {
        if (t < 1) return;
        const int tt = t - 1;
        const float* A_x = h0 + (tt & 1) * HB + b;        // x = h0[tt]
        const float* A_h = h1 + ((tt + 1) & 1) * HB + b;  // h1[tt-1]
        float*       hn  = h1 + (tt & 1) * HB;            // h1[tt]

        const float4* wx[8];
        const float4* wh[8];
#pragma unroll
        for (int r = 0; r < 8; ++r) {
            int row = (r & 3) * H + j0 + (r >> 2);
            wx[r] = (const float4*)(Wih1 + (size_t)row * H);
            wh[r] = (const float4*)(Whh1 + (size_t)row * H);
        }
        gemm_tb(acc, A_x, wx, H / 4);
        gemm_tb(acc, A_h, wh, H / 4);
        epilogue(acc, b1, j0, c1, hn, b, hmax, last, tt);
    }
}

// ---------------- final: logits[b][cls] = sum_j hmax[j][b] * Wout[cls][j] + bout ----
__global__ __launch_bounds__(64) void k_out(const float* __restrict__ hmax,
                                            const float* __restrict__ Wout,
                                            const float* __restrict__ bout,
                                            float* __restrict__ out) {
    const int b = blockIdx.x * 64 + threadIdx.x;
    float a[NC] = {0.f, 0.f, 0.f, 0.f, 0.f};
    const float* hm = hmax + b;
    for (int j = 0; j < H; ++j) {
        float hv = hm[j * B];
#pragma unroll
        for (int cls = 0; cls < NC; ++cls)
            a[cls] = fmaf(hv, Wout[cls * H + j], a[cls]);
    }
#pragma unroll
    for (int cls = 0; cls < NC; ++cls)
        out[b * NC + cls] = a[cls] + bout[cls];
}

// ---------------- launch ----------------
extern "C" void kernel_launch(void* const* d_in, const int* in_sizes, int n_in,
                              void* d_out, int out_size, void* d_ws, size_t ws_size,
                              hipStream_t stream) {
    const int*   X    = (const int*)  d_in[0];
    const float* emb  = (const float*)d_in[1];
    const float* Wih0 = (const float*)d_in[2];
    const float* Whh0 = (const float*)d_in[3];
    const float* b0   = (const float*)d_in[4];
    const float* Wih1 = (const float*)d_in[5];
    const float* Whh1 = (const float*)d_in[6];
    const float* b1   = (const float*)d_in[7];
    const float* Wout = (const float*)d_in[8];
    const float* bout = (const float*)d_in[9];
    float* out = (float*)d_out;
    float* ws  = (float*)d_ws;

    float* hmax = ws + 6 * HB;
    int*   last = (int*)(ws + 7 * HB);

    k_init<<<(7 * HB + 255) / 256, 256, 0, stream>>>(ws, X, last);

    // Launch L_t computes layer0(t) and layer1(t-1); t = 0..T inclusive.
    for (int t = 0; t <= T; ++t) {
        k_step<<<512, 256, 0, stream>>>(t, X, emb, Wih0, Whh0, b0,
                                        Wih1, Whh1, b1, ws);
    }

    k_out<<<4, 64, 0, stream>>>(hmax, Wout, bout, out);
}